// Round 1
// baseline (319.525 us; speedup 1.0000x reference)
//
#include <hip/hip_runtime.h>

#define BC 16
#define NN 2048
#define FF 128
#define DD 128
#define NEDGES 65536
#define NEG_INF -1e16f
#define LEAK 0.1f

// ---------------- Kernel 1: z[b,n,:] = h[b,n,:] @ W  ----------------
// one block (128 threads) per (b,n); thread d owns output dim d.
__global__ void __launch_bounds__(128) zgemm_kernel(const float* __restrict__ h,
                                                    const float* __restrict__ W,
                                                    float* __restrict__ z) {
    __shared__ float hs[FF];
    const int bn = blockIdx.x;          // b*NN + n
    const int d = threadIdx.x;
    hs[d] = h[(size_t)bn * FF + d];
    __syncthreads();
    float acc = 0.f;
#pragma unroll 8
    for (int f = 0; f < FF; ++f)
        acc += hs[f] * W[f * DD + d];   // W read coalesced across d
    z[(size_t)bn * DD + d] = acc;
}

// ---------------- Kernel 2: build dedup adjacency bitmask ----------------
__global__ void mask_kernel(const int* __restrict__ row, const int* __restrict__ col,
                            unsigned int* __restrict__ mask) {
    const int e = blockIdx.x * blockDim.x + threadIdx.x;
    if (e < NEDGES) {
        const unsigned int key = (unsigned int)row[e] * NN + (unsigned int)col[e];
        atomicOr(&mask[key >> 5], 1u << (key & 31u));
    }
}

// ---------------- Kernel 3: sparse attention + aggregation ----------------
// one block (128 threads = 2 waves) per (b,n).
__global__ void __launch_bounds__(128) gat_kernel(const float* __restrict__ z,
                                                  const unsigned int* __restrict__ mask,
                                                  float* __restrict__ out) {
    __shared__ float zn[DD];
    __shared__ int hits[NN];       // 8 KB — worst case a full row of edges
    __shared__ float scores[NN];   // 8 KB
    __shared__ float red[128];
    __shared__ int nhits;

    const int bn = blockIdx.x;
    const int n = bn & (NN - 1);
    const int b = bn >> 11;
    const int tid = threadIdx.x;

    if (tid == 0) nhits = 0;
    zn[tid] = z[(size_t)bn * DD + tid];
    __syncthreads();

    // scan this row's 64 mask words, collect set bits
    const unsigned int* mrow = mask + n * (NN / 32);
    for (int w = tid; w < NN / 32; w += 128) {
        unsigned int bits = mrow[w];
        while (bits) {
            const int bit = __ffs(bits) - 1;
            bits &= bits - 1;
            const int idx = atomicAdd(&nhits, 1);
            hits[idx] = w * 32 + bit;
        }
    }
    __syncthreads();
    const int nh = nhits;

    // score phase: one wave per hit, dot over 128 dims (2 elems/lane)
    const int wave = tid >> 6;
    const int lane = tid & 63;
    const float* zb = z + (size_t)b * NN * DD;
    for (int i = wave; i < nh; i += 2) {
        const float* zm = zb + (size_t)hits[i] * DD;
        float part = zn[lane] * zm[lane] + zn[lane + 64] * zm[lane + 64];
#pragma unroll
        for (int off = 32; off > 0; off >>= 1)
            part += __shfl_xor(part, off, 64);
        if (lane == 0) {
            float s = part;
            s = s > 0.f ? s : LEAK * s;     // leaky_relu(0.1)
            if (s == 0.f) s = NEG_INF;      // masked_fill(att == 0)
            scores[i] = s;
        }
    }
    __syncthreads();

    // block max
    float mx = NEG_INF;
    for (int i = tid; i < nh; i += 128) mx = fmaxf(mx, scores[i]);
    red[tid] = mx;
    __syncthreads();
#pragma unroll
    for (int s = 64; s > 0; s >>= 1) {
        if (tid < s) red[tid] = fmaxf(red[tid], red[tid + s]);
        __syncthreads();
    }
    mx = red[0];
    __syncthreads();

    if (mx > 0.5f * NEG_INF) {
        // normal path: sum of exp
        float sum = 0.f;
        for (int i = tid; i < nh; i += 128) sum += expf(scores[i] - mx);
        red[tid] = sum;
        __syncthreads();
#pragma unroll
        for (int s = 64; s > 0; s >>= 1) {
            if (tid < s) red[tid] += red[tid + s];
            __syncthreads();
        }
        const float inv = 1.f / red[0];
        __syncthreads();
        for (int i = tid; i < nh; i += 128)
            scores[i] = expf(scores[i] - mx) * inv;   // p_i
        __syncthreads();

        // aggregate: thread d accumulates out[b,n,d]
        float acc = 0.f;
        for (int i = 0; i < nh; ++i)
            acc += scores[i] * zb[(size_t)hits[i] * DD + tid];
        out[(size_t)bn * DD + tid] = acc;
    } else {
        // row had no valid edge: softmax over all-(-1e16) row -> uniform 1/N
        float acc = 0.f;
        for (int m = 0; m < NN; ++m)
            acc += zb[(size_t)m * DD + tid];
        out[(size_t)bn * DD + tid] = acc * (1.f / NN);
    }
}

// ---------------- launcher ----------------
extern "C" void kernel_launch(void* const* d_in, const int* in_sizes, int n_in,
                              void* d_out, int out_size, void* d_ws, size_t ws_size,
                              hipStream_t stream) {
    const float* h = (const float*)d_in[0];
    const float* W = (const float*)d_in[1];
    const int* row = (const int*)d_in[2];
    const int* col = (const int*)d_in[3];
    float* out = (float*)d_out;

    float* z = (float*)d_ws;                               // 16 MB
    unsigned int* mask =
        (unsigned int*)((char*)d_ws + (size_t)BC * NN * DD * sizeof(float));  // 512 KB

    hipMemsetAsync(mask, 0, (size_t)NN * NN / 8, stream);
    zgemm_kernel<<<BC * NN, 128, 0, stream>>>(h, W, z);
    mask_kernel<<<NEDGES / 256, 256, 0, stream>>>(row, col, mask);
    gat_kernel<<<BC * NN, 128, 0, stream>>>(z, mask, out);
}

// Round 2
// 220.432 us; speedup vs baseline: 1.4495x; 1.4495x over previous
//
#include <hip/hip_runtime.h>

#define BC 16
#define NN 2048
#define FF 128
#define DD 128
#define NEDGES 65536
#define NEG_INF -1e16f
#define LEAK 0.1f
#define CAP 2048   // max in-degree we can buffer (worst case = full row)

// ---------------- Kernel 1: z = h @ W  (register-tiled fp32 GEMM) --------
// block = 256 threads computes a [32 rows x 128 cols] tile of z.
// thread (tid) -> cols c0..c0+3 (c0 = (tid&31)*4), rows r0..r0+3 (r0=(tid>>5)*4).
__global__ void __launch_bounds__(256) zgemm_kernel(const float* __restrict__ h,
                                                    const float* __restrict__ W,
                                                    float* __restrict__ z) {
    __shared__ float hs[32][FF];   // 16 KB
    const int tid = threadIdx.x;
    const size_t row0 = (size_t)blockIdx.x * 32;

    // stage 32 h-rows: 4096 floats = 1024 float4, 4 per thread, coalesced
    const float4* hv = (const float4*)(h + row0 * FF);
    float4* hsv = (float4*)&hs[0][0];
#pragma unroll
    for (int i = 0; i < 4; ++i) hsv[tid + 256 * i] = hv[tid + 256 * i];
    __syncthreads();

    const int c0 = (tid & 31) * 4;
    const int r0 = (tid >> 5) * 4;
    float acc[4][4] = {};

    for (int f = 0; f < FF; f += 4) {
        // a-fragment: 4 rows x 4 k  (LDS b128, broadcast within row-group)
        float4 a0 = *(const float4*)&hs[r0 + 0][f];
        float4 a1 = *(const float4*)&hs[r0 + 1][f];
        float4 a2 = *(const float4*)&hs[r0 + 2][f];
        float4 a3 = *(const float4*)&hs[r0 + 3][f];
        // b-fragment: 4 k x 4 cols (coalesced global, L1-resident)
        float4 b0 = *(const float4*)&W[(f + 0) * DD + c0];
        float4 b1 = *(const float4*)&W[(f + 1) * DD + c0];
        float4 b2 = *(const float4*)&W[(f + 2) * DD + c0];
        float4 b3 = *(const float4*)&W[(f + 3) * DD + c0];
#pragma unroll
        for (int r = 0; r < 4; ++r) {
            float4 a = r == 0 ? a0 : (r == 1 ? a1 : (r == 2 ? a2 : a3));
            acc[r][0] += a.x * b0.x + a.y * b1.x + a.z * b2.x + a.w * b3.x;
            acc[r][1] += a.x * b0.y + a.y * b1.y + a.z * b2.y + a.w * b3.y;
            acc[r][2] += a.x * b0.z + a.y * b1.z + a.z * b2.z + a.w * b3.z;
            acc[r][3] += a.x * b0.w + a.y * b1.w + a.z * b2.w + a.w * b3.w;
        }
    }
#pragma unroll
    for (int r = 0; r < 4; ++r) {
        float4 o = make_float4(acc[r][0], acc[r][1], acc[r][2], acc[r][3]);
        *(float4*)&z[(row0 + r0 + r) * DD + c0] = o;
    }
}

// ---------------- Kernel 2: dedup adjacency bitmask ----------------
__global__ void mask_kernel(const int* __restrict__ row, const int* __restrict__ col,
                            unsigned int* __restrict__ mask) {
    const int e = blockIdx.x * blockDim.x + threadIdx.x;
    if (e < NEDGES) {
        const unsigned int key = (unsigned int)row[e] * NN + (unsigned int)col[e];
        atomicOr(&mask[key >> 5], 1u << (key & 31u));
    }
}

// ---------------- Kernel 3: sparse attention + aggregation ----------------
// one block (128 threads = 2 waves) per (b,n). Online softmax over chunks of
// 32 edges; 4 threads per edge-score; 32 loads in flight for aggregation.
__global__ void __launch_bounds__(128) gat_kernel(const float* __restrict__ z,
                                                  const unsigned int* __restrict__ mask,
                                                  float* __restrict__ out) {
    __shared__ float zn[DD];
    __shared__ int hits[CAP];     // 8 KB
    __shared__ float cs[32];      // chunk scores
    __shared__ float cp[32];      // chunk probs
    __shared__ int nhits;

    const int bn = blockIdx.x;
    const int n = bn & (NN - 1);
    const int b = bn >> 11;
    const int tid = threadIdx.x;

    if (tid == 0) nhits = 0;
    zn[tid] = z[(size_t)bn * DD + tid];
    __syncthreads();

    // collect this row's edges from the bitmask (64 words)
    if (tid < NN / 32) {
        unsigned int bits = mask[n * (NN / 32) + tid];
        while (bits) {
            const int bit = __ffs(bits) - 1;
            bits &= bits - 1;
            hits[atomicAdd(&nhits, 1)] = tid * 32 + bit;
        }
    }
    __syncthreads();
    const int nh = nhits;
    const float* zb = z + (size_t)b * NN * DD;

    float m = NEG_INF, l = 0.f, acc = 0.f;

    if (nh > 0) {
        // pad hit list to a multiple of 32 with a valid (but score-masked) index
        const int npad = (nh + 31) & ~31;
        for (int i = nh + tid; i < npad; i += 128) hits[i] = hits[0];
        __syncthreads();

        const int g = tid >> 2;     // edge slot 0..31
        const int q = tid & 3;      // quarter of the 128-dim dot

        for (int c0 = 0; c0 < nh; c0 += 32) {
            // ---- score: 4 threads per edge, float4 dot, 2-step shuffle reduce
            {
                const float* zm = zb + (size_t)hits[c0 + g] * DD + q * 32;
                const float* zq = &zn[q * 32];
                float part = 0.f;
#pragma unroll
                for (int j = 0; j < 8; ++j) {
                    float4 a = *(const float4*)(zq + 4 * j);
                    float4 v = *(const float4*)(zm + 4 * j);
                    part += a.x * v.x + a.y * v.y + a.z * v.z + a.w * v.w;
                }
                part += __shfl_xor(part, 1, 64);
                part += __shfl_xor(part, 2, 64);
                if (q == 0) {
                    float s = part > 0.f ? part : LEAK * part;  // leaky_relu(0.1)
                    if (s == 0.f) s = NEG_INF;                  // masked_fill(att==0)
                    if (c0 + g >= nh) s = NEG_INF;              // pad slots
                    cs[g] = s;
                }
            }
            __syncthreads();

            // ---- chunk max (uniform LDS broadcast scan)
            float cmax = cs[0];
#pragma unroll
            for (int i = 1; i < 32; ++i) cmax = fmaxf(cmax, cs[i]);
            const float mnew = fmaxf(m, cmax);

            if (tid < 32) cp[tid] = __expf(cs[tid] - mnew);
            __syncthreads();

            float psum = 0.f;
#pragma unroll
            for (int i = 0; i < 32; ++i) psum += cp[i];

            const float alpha = __expf(m - mnew);   // 0 when m==NEG_INF, mnew real
            l = l * alpha + psum;
            acc *= alpha;
            // ---- aggregate: thread owns dim `tid`; 32 independent loads in flight
#pragma unroll
            for (int i = 0; i < 32; ++i)
                acc += cp[i] * zb[(size_t)hits[c0 + i] * DD + tid];
            m = mnew;
            __syncthreads();   // cs/cp reused next chunk
        }
    }

    if (m > 0.5f * NEG_INF) {
        out[(size_t)bn * DD + tid] = acc / l;
    } else {
        // no valid edges: softmax over uniform -1e16 row -> mean of all z rows
        float s = 0.f;
#pragma unroll 4
        for (int mm = 0; mm < NN; ++mm) s += zb[(size_t)mm * DD + tid];
        out[(size_t)bn * DD + tid] = s * (1.f / NN);
    }
}

// ---------------- launcher ----------------
extern "C" void kernel_launch(void* const* d_in, const int* in_sizes, int n_in,
                              void* d_out, int out_size, void* d_ws, size_t ws_size,
                              hipStream_t stream) {
    const float* h = (const float*)d_in[0];
    const float* W = (const float*)d_in[1];
    const int* row = (const int*)d_in[2];
    const int* col = (const int*)d_in[3];
    float* out = (float*)d_out;

    float* z = (float*)d_ws;                               // 16 MB
    unsigned int* mask =
        (unsigned int*)((char*)d_ws + (size_t)BC * NN * DD * sizeof(float));  // 512 KB

    hipMemsetAsync(mask, 0, (size_t)NN * NN / 8, stream);
    zgemm_kernel<<<(BC * NN) / 32, 256, 0, stream>>>(h, W, z);
    mask_kernel<<<NEDGES / 256, 256, 0, stream>>>(row, col, mask);
    gat_kernel<<<BC * NN, 128, 0, stream>>>(z, mask, out);
}